// Round 1
// baseline (20447.690 us; speedup 1.0000x reference)
//
#include <hip/hip_runtime.h>
#include <hip/hip_bf16.h>

// Problem constants
#define BATCH   64
#define SEQ     512
#define DMODEL  256
#define HIDDEN  512
#define G3      1536      // 3*HIDDEN
#define NBLK    128       // scan blocks; 512 hidden units / 128 = 4 units/block
#define UPB     4         // units per block
#define CPB     12        // Wh columns per block (3 gates * UPB)
#define SCAN_T  512       // scan threads (8 waves)

// ---------------------------------------------------------------------------
// Pack Wh slices: whp[blk][c][k] = Wh[k][ g*512 + blk*4 + u ]  (c = g*4+u)
// Contiguous in k so the scan kernel's wave-uniform weight reads become s_load.
// ---------------------------------------------------------------------------
__global__ __launch_bounds__(512) void prep_wh(const float* __restrict__ Wh,
                                               float* __restrict__ whp) {
    int t = blockIdx.x * 512 + threadIdx.x;      // 0 .. 786431
    int k   = t & 511;
    int cb  = t >> 9;          // blk*12 + c
    int c   = cb % 12;
    int blk = cb / 12;
    int u = c & 3, g = c >> 2;
    whp[t] = Wh[(long)k * G3 + g * HIDDEN + blk * UPB + u];
}

// ---------------------------------------------------------------------------
// xg GEMM: xg[row][col] = emb[ids[row]] . Wx[:,col] + bx[col]
// row = b*512 + s (natural ids order). M=32768, N=1536, K=256.
// 64x64 tile per block, K-chunks of 64, 4x4 microtile per thread.
// ---------------------------------------------------------------------------
__global__ __launch_bounds__(256) void xg_gemm(const int* __restrict__ ids,
                                               const float* __restrict__ emb,
                                               const float* __restrict__ Wx,
                                               const float* __restrict__ bx,
                                               float* __restrict__ xg) {
    __shared__ float At[64][68];   // A-tile transposed: At[k][m], padded
    __shared__ float Bs[64][68];   // B-tile: Bs[k][n], padded
    __shared__ int   sids[64];

    const int tid = threadIdx.x;
    const int nb = blockIdx.x;     // 0..23
    const int mb = blockIdx.y;     // 0..511
    const int tn = tid & 15;       // col group
    const int tm = tid >> 4;       // row group

    if (tid < 64) sids[tid] = ids[mb * 64 + tid];
    __syncthreads();

    float acc[4][4];
#pragma unroll
    for (int i = 0; i < 4; ++i)
#pragma unroll
        for (int j = 0; j < 4; ++j) acc[i][j] = 0.f;

    for (int kb = 0; kb < 256; kb += 64) {
#pragma unroll
        for (int p = 0; p < 4; ++p) {
            int row = p * 16 + tm;
            float4 av = *(const float4*)(emb + (long)sids[row] * DMODEL + kb + tn * 4);
            At[tn * 4 + 0][row] = av.x;
            At[tn * 4 + 1][row] = av.y;
            At[tn * 4 + 2][row] = av.z;
            At[tn * 4 + 3][row] = av.w;
            int krow = p * 16 + tm;
            float4 bv = *(const float4*)(Wx + (long)(kb + krow) * G3 + nb * 64 + tn * 4);
            *(float4*)&Bs[krow][tn * 4] = bv;
        }
        __syncthreads();
#pragma unroll
        for (int k = 0; k < 64; ++k) {
            float4 a4 = *(const float4*)&At[k][tm * 4];
            float4 b4 = *(const float4*)&Bs[k][tn * 4];
            float aa[4] = {a4.x, a4.y, a4.z, a4.w};
            float bb[4] = {b4.x, b4.y, b4.z, b4.w};
#pragma unroll
            for (int i = 0; i < 4; ++i)
#pragma unroll
                for (int j = 0; j < 4; ++j)
                    acc[i][j] = fmaf(aa[i], bb[j], acc[i][j]);
        }
        __syncthreads();
    }

    float4 bxv = *(const float4*)(bx + nb * 64 + tn * 4);
#pragma unroll
    for (int i = 0; i < 4; ++i) {
        int row = mb * 64 + tm * 4 + i;
        float4 o;
        o.x = acc[i][0] + bxv.x;
        o.y = acc[i][1] + bxv.y;
        o.z = acc[i][2] + bxv.z;
        o.w = acc[i][3] + bxv.w;
        *(float4*)(xg + (long)row * G3 + nb * 64 + tn * 4) = o;
    }
}

// ---------------------------------------------------------------------------
// GRU scan. 128 blocks x 512 threads. Block owns 4 hidden units (12 Wh cols,
// held as packed slice read via scalar loads). h stored transposed hT[k][b]
// in ws, double-buffered. Grid barrier per step: monotonic device-scope
// atomic counter. 128 blocks <= 256 CUs => all co-resident => no deadlock.
// ---------------------------------------------------------------------------
__global__ __launch_bounds__(512) void gru_scan(const float* __restrict__ whp,
                                                const float* __restrict__ xg,
                                                const float* __restrict__ bh,
                                                float* hbuf,
                                                unsigned* counter) {
    const int tid = threadIdx.x;
    const int blk = blockIdx.x;
    const int b   = tid & 63;                               // lane = batch
    const int wu  = __builtin_amdgcn_readfirstlane(tid >> 6); // wave id 0..7 (SGPR)

    __shared__ float part[8][CPB][64];   // 24 KB partial sums

    const float* whp_blk = whp + blk * (CPB * HIDDEN) + wu * 64; // + c*512 + i

    // gate-thread setup (first 4 waves: 64 b x 4 units)
    const int gu = tid >> 6;
    int jg = 0;
    float bhr = 0.f, bhz = 0.f, bhn = 0.f;
    long xgb = 0;
    if (tid < 256) {
        jg = blk * UPB + gu;
        bhr = bh[jg];
        bhz = bh[HIDDEN + jg];
        bhn = bh[2 * HIDDEN + jg];
        xgb = (long)b * SEQ * G3;
    }

#pragma unroll 1
    for (int t = 0; t < SEQ; ++t) {
        float* hcur = hbuf + (t & 1) * (HIDDEN * BATCH);
        float* hnxt = hbuf + ((t + 1) & 1) * (HIDDEN * BATCH);

        // prefetch gate inputs (uncoalesced but tiny; issued early)
        float xr = 0.f, xz = 0.f, xn = 0.f, hprev = 0.f;
        if (tid < 256) {
            const float* xp = xg + xgb + (long)t * G3;
            xr = xp[jg];
            xz = xp[HIDDEN + jg];
            xn = xp[2 * HIDDEN + jg];
            hprev = hcur[jg * 64 + b];
        }

        // load this wave's k-slice of h: hT[k][b], coalesced
        float hreg[64];
#pragma unroll
        for (int i = 0; i < 64; ++i) hreg[i] = hcur[(wu * 64 + i) * 64 + b];

        float acc[CPB];
#pragma unroll
        for (int c = 0; c < CPB; ++c) acc[c] = 0.f;

        // partial hg: weights are wave-uniform -> SMEM path, VALU does fmac v,s,v
#pragma unroll
        for (int i = 0; i < 64; ++i) {
            float hv = hreg[i];
#pragma unroll
            for (int c = 0; c < CPB; ++c)
                acc[c] = fmaf(hv, whp_blk[c * HIDDEN + i], acc[c]);
        }

#pragma unroll
        for (int c = 0; c < CPB; ++c) part[wu][c][b] = acc[c];
        __syncthreads();

        if (tid < 256) {
            float hgr = bhr, hgz = bhz, hgn = bhn;
#pragma unroll
            for (int ww = 0; ww < 8; ++ww) {
                hgr += part[ww][gu][b];
                hgz += part[ww][4 + gu][b];
                hgn += part[ww][8 + gu][b];
            }
            float r = 1.f / (1.f + expf(-(xr + hgr)));
            float z = 1.f / (1.f + expf(-(xz + hgz)));
            float nn = tanhf(xn + r * hgn);
            hnxt[jg * 64 + b] = (1.f - z) * nn + z * hprev;
        }
        __syncthreads();

        if (t < SEQ - 1) {
            if (tid == 0) {
                __hip_atomic_fetch_add(counter, 1u, __ATOMIC_RELEASE,
                                       __HIP_MEMORY_SCOPE_AGENT);
                const unsigned target = (unsigned)NBLK * (unsigned)(t + 1);
                while (__hip_atomic_load(counter, __ATOMIC_ACQUIRE,
                                         __HIP_MEMORY_SCOPE_AGENT) < target)
                    __builtin_amdgcn_s_sleep(2);
            }
            __syncthreads();
        }
    }
}

// ---------------------------------------------------------------------------
// head: logits[b][n] = sum_k hT[k][b] * Wo[k][n] + bo[n]
// ---------------------------------------------------------------------------
__global__ void head_kernel(const float* __restrict__ hT,
                            const float* __restrict__ Wo,
                            const float* __restrict__ bo,
                            float* __restrict__ out) {
    int tid = threadIdx.x;        // 128 threads
    int b = tid >> 1, n = tid & 1;
    float acc = bo[n];
#pragma unroll 8
    for (int k = 0; k < HIDDEN; ++k)
        acc = fmaf(hT[k * 64 + b], Wo[k * 2 + n], acc);
    out[b * 2 + n] = acc;
}

// ---------------------------------------------------------------------------
extern "C" void kernel_launch(void* const* d_in, const int* in_sizes, int n_in,
                              void* d_out, int out_size, void* d_ws, size_t ws_size,
                              hipStream_t stream) {
    (void)in_sizes; (void)n_in; (void)out_size; (void)ws_size;
    const int*   ids = (const int*)  d_in[0];
    const float* emb = (const float*)d_in[1];
    const float* Wx  = (const float*)d_in[2];
    const float* Wh  = (const float*)d_in[3];
    const float* bx  = (const float*)d_in[4];
    const float* bh  = (const float*)d_in[5];
    const float* Wo  = (const float*)d_in[6];
    const float* bo  = (const float*)d_in[7];
    float* out = (float*)d_out;

    char* ws = (char*)d_ws;
    // ws layout: [counter 256B][hbuf 2*512*64 f32 = 256KB][whp 3MB][xg 192MB]
    unsigned* counter = (unsigned*)ws;
    float* hbuf = (float*)(ws + 256);
    float* whp  = (float*)(ws + 256 + 2 * HIDDEN * BATCH * 4);
    float* xg   = (float*)(ws + 256 + 2 * HIDDEN * BATCH * 4 + NBLK * CPB * HIDDEN * 4);

    // zero barrier counter + both h buffers (h0 must be zeros)
    hipMemsetAsync(ws, 0, 256 + 2 * HIDDEN * BATCH * 4, stream);

    prep_wh<<<dim3(1536), dim3(512), 0, stream>>>(Wh, whp);
    xg_gemm<<<dim3(24, 512), dim3(256), 0, stream>>>(ids, emb, Wx, bx, xg);
    gru_scan<<<dim3(NBLK), dim3(SCAN_T), 0, stream>>>(whp, xg, bh, hbuf, counter);
    head_kernel<<<dim3(1), dim3(128), 0, stream>>>(hbuf, Wo, bo, out);
}

// Round 2
// 7036.034 us; speedup vs baseline: 2.9061x; 2.9061x over previous
//
#include <hip/hip_runtime.h>
#include <hip/hip_bf16.h>

// Problem constants
#define BATCH   64
#define SEQ     512
#define DMODEL  256
#define HIDDEN  512
#define G3      1536      // 3*HIDDEN
#define NBLK    128       // scan blocks; 512 hidden units / 128 = 4 units/block
#define UPB     4         // units per block
#define CPB     12        // Wh columns per block (3 gates * UPB)

// ---------------------------------------------------------------------------
// Pack Wh slices: whp[blk][c][k] = Wh[k][ g*512 + blk*4 + u ]  (c = g*4+u)
// Contiguous in k so the scan kernel's wave-uniform weight reads scalarize
// (s_load from L2-resident slice; 24 KB/block stays hot — no fences evict it).
// ---------------------------------------------------------------------------
__global__ __launch_bounds__(512) void prep_wh(const float* __restrict__ Wh,
                                               float* __restrict__ whp) {
    int t = blockIdx.x * 512 + threadIdx.x;      // 0 .. 786431
    int k   = t & 511;
    int cb  = t >> 9;          // blk*12 + c
    int c   = cb % 12;
    int blk = cb / 12;
    int u = c & 3, g = c >> 2;
    whp[t] = Wh[(long)k * G3 + g * HIDDEN + blk * UPB + u];
}

// ---------------------------------------------------------------------------
// Zero the barrier flags with agent-scope (L3-coherent) stores so the scan's
// L2-bypassing polls are guaranteed to see them (plain memset could leave the
// zeros dirty in one XCD's L2 while polls read stale 0xAA from L3).
// ---------------------------------------------------------------------------
__global__ void init_flags(unsigned* flags) {
    __hip_atomic_store(&flags[threadIdx.x], 0u, __ATOMIC_RELAXED,
                       __HIP_MEMORY_SCOPE_AGENT);
}

// ---------------------------------------------------------------------------
// xg GEMM: xg[row][col] = emb[ids[row]] . Wx[:,col] + bx[col]
// row = b*512 + s (natural ids order). M=32768, N=1536, K=256.
// 64x64 tile per block, K-chunks of 64, 4x4 microtile per thread.
// ---------------------------------------------------------------------------
__global__ __launch_bounds__(256) void xg_gemm(const int* __restrict__ ids,
                                               const float* __restrict__ emb,
                                               const float* __restrict__ Wx,
                                               const float* __restrict__ bx,
                                               float* __restrict__ xg) {
    __shared__ float At[64][68];   // A-tile transposed: At[k][m], padded
    __shared__ float Bs[64][68];   // B-tile: Bs[k][n], padded
    __shared__ int   sids[64];

    const int tid = threadIdx.x;
    const int nb = blockIdx.x;     // 0..23
    const int mb = blockIdx.y;     // 0..511
    const int tn = tid & 15;       // col group
    const int tm = tid >> 4;       // row group

    if (tid < 64) sids[tid] = ids[mb * 64 + tid];
    __syncthreads();

    float acc[4][4];
#pragma unroll
    for (int i = 0; i < 4; ++i)
#pragma unroll
        for (int j = 0; j < 4; ++j) acc[i][j] = 0.f;

    for (int kb = 0; kb < 256; kb += 64) {
#pragma unroll
        for (int p = 0; p < 4; ++p) {
            int row = p * 16 + tm;
            float4 av = *(const float4*)(emb + (long)sids[row] * DMODEL + kb + tn * 4);
            At[tn * 4 + 0][row] = av.x;
            At[tn * 4 + 1][row] = av.y;
            At[tn * 4 + 2][row] = av.z;
            At[tn * 4 + 3][row] = av.w;
            int krow = p * 16 + tm;
            float4 bv = *(const float4*)(Wx + (long)(kb + krow) * G3 + nb * 64 + tn * 4);
            *(float4*)&Bs[krow][tn * 4] = bv;
        }
        __syncthreads();
#pragma unroll
        for (int k = 0; k < 64; ++k) {
            float4 a4 = *(const float4*)&At[k][tm * 4];
            float4 b4 = *(const float4*)&Bs[k][tn * 4];
            float aa[4] = {a4.x, a4.y, a4.z, a4.w};
            float bb[4] = {b4.x, b4.y, b4.z, b4.w};
#pragma unroll
            for (int i = 0; i < 4; ++i)
#pragma unroll
                for (int j = 0; j < 4; ++j)
                    acc[i][j] = fmaf(aa[i], bb[j], acc[i][j]);
        }
        __syncthreads();
    }

    float4 bxv = *(const float4*)(bx + nb * 64 + tn * 4);
#pragma unroll
    for (int i = 0; i < 4; ++i) {
        int row = mb * 64 + tm * 4 + i;
        float4 o;
        o.x = acc[i][0] + bxv.x;
        o.y = acc[i][1] + bxv.y;
        o.z = acc[i][2] + bxv.z;
        o.w = acc[i][3] + bxv.w;
        *(float4*)(xg + (long)row * G3 + nb * 64 + tn * 4) = o;
    }
}

// ---------------------------------------------------------------------------
// GRU scan v2. 128 blocks x 512 threads. Key changes vs v1:
//  * NO acquire fences / no L2 invalidation anywhere in the loop. All
//    cross-block data (h, flags) moves via agent-scope RELAXED atomics,
//    which bypass L1/L2 and are served by L3 (the multi-XCD coherence
//    point). Weights (L2) and xg (L1/L2) stay cached across all 512 steps.
//  * Flag-array barrier instead of one RMW counter: block stores
//    flags[blk]=t+1 (h-stores already drained by __syncthreads' vmcnt(0));
//    every wave polls all 128 flags (2 per lane) — no RMW serialization,
//    no extra __syncthreads after the poll.
//  * t==0 skips the h.Wh matvec entirely (h0=0 => hg=bh), so hbuf needs
//    no initialization and is only ever touched with L3-coherent ops.
// Ordering note: formally the flag handoff is relaxed/relaxed, but at ISA
// level the producer's h-stores hit L3 before its flag store (barrier's
// pre-s_barrier vmcnt(0) drain), and consumer h-loads issue after the poll
// exits and also read L3 — sound on CDNA4.
// ---------------------------------------------------------------------------
__global__ __launch_bounds__(512, 2) void gru_scan(const float* __restrict__ whp,
                                                   const float* __restrict__ xg,
                                                   const float* __restrict__ bh,
                                                   float* hbuf,
                                                   unsigned* flags) {
    const int tid  = threadIdx.x;
    const int blk  = blockIdx.x;
    const int lane = tid & 63;
    const int b    = lane;                                    // lane = batch
    const int wu   = __builtin_amdgcn_readfirstlane(tid >> 6); // wave 0..7

    __shared__ float part[8][CPB][64];   // 24 KB partial sums
    __shared__ float hl[UPB][64];        // this block's own h slice (hprev)

    const float* wb = whp + blk * (CPB * HIDDEN) + wu * 64;   // + c*512 + i

    // gate-thread setup (first 4 waves: 64 b x 4 units)
    const int gu = tid >> 6;
    int jg = 0;
    float bhr = 0.f, bhz = 0.f, bhn = 0.f;
    const float* xgp = nullptr;
    if (tid < 256) {
        jg  = blk * UPB + gu;
        bhr = bh[jg];
        bhz = bh[HIDDEN + jg];
        bhn = bh[2 * HIDDEN + jg];
        xgp = xg + (long)b * SEQ * G3;
        hl[gu][b] = 0.f;                 // h0 = 0
    }
    __syncthreads();

#pragma unroll 1
    for (int t = 0; t < SEQ; ++t) {
        float* hcur = hbuf + (t & 1) * (HIDDEN * BATCH);
        float* hnxt = hbuf + ((t + 1) & 1) * (HIDDEN * BATCH);

        // gate inputs: normal cached loads (xg is read-only, stays in L1/L2);
        // issued early so the ~600cyc latency hides behind the matvec.
        float xr = 0.f, xz = 0.f, xn = 0.f, hprev = 0.f;
        if (tid < 256) {
            const float* xp = xgp + (long)t * G3;
            xr = xp[jg];
            xz = xp[HIDDEN + jg];
            xn = xp[2 * HIDDEN + jg];
            hprev = hl[gu][b];
        }

        if (t > 0) {
            // this wave's 64-k slice of h: L3-coherent loads, all independent
            const float* hc = hcur + (wu * 64) * 64 + b;
            float hreg[64];
#pragma unroll
            for (int i = 0; i < 64; ++i)
                hreg[i] = __hip_atomic_load(hc + (long)i * 64, __ATOMIC_RELAXED,
                                            __HIP_MEMORY_SCOPE_AGENT);

            float acc[CPB];
#pragma unroll
            for (int c = 0; c < CPB; ++c) acc[c] = 0.f;

            // weights are wave-uniform -> SMEM path (s_load from hot L2)
#pragma unroll
            for (int i = 0; i < 64; ++i) {
                float hv = hreg[i];
#pragma unroll
                for (int c = 0; c < CPB; ++c)
                    acc[c] = fmaf(hv, wb[c * HIDDEN + i], acc[c]);
            }
#pragma unroll
            for (int c = 0; c < CPB; ++c) part[wu][c][b] = acc[c];
        } else {
            // h0 == 0  =>  hg = bh; no h reads at all
#pragma unroll
            for (int c = 0; c < CPB; ++c) part[wu][c][b] = 0.f;
        }
        __syncthreads();

        if (tid < 256) {
            float hgr = bhr, hgz = bhz, hgn = bhn;
#pragma unroll
            for (int ww = 0; ww < 8; ++ww) {
                hgr += part[ww][gu][b];
                hgz += part[ww][4 + gu][b];
                hgn += part[ww][8 + gu][b];
            }
            float r  = 1.f / (1.f + expf(-(xr + hgr)));
            float z  = 1.f / (1.f + expf(-(xz + hgz)));
            float nn = tanhf(xn + r * hgn);
            float hnew = (1.f - z) * nn + z * hprev;
            // L3-coherent write-through; no L2 dirty state
            __hip_atomic_store(&hnxt[jg * 64 + b], hnew, __ATOMIC_RELAXED,
                               __HIP_MEMORY_SCOPE_AGENT);
            hl[gu][b] = hnew;
        }
        // drains every wave's h-stores (vmcnt(0) before s_barrier) and
        // publishes hl for next iteration
        __syncthreads();

        if (t < SEQ - 1) {
            if (tid == 0)
                __hip_atomic_store(&flags[blk], (unsigned)(t + 1),
                                   __ATOMIC_RELAXED, __HIP_MEMORY_SCOPE_AGENT);
            const unsigned tgt = (unsigned)(t + 1);
            for (;;) {
                unsigned f0 = __hip_atomic_load(&flags[lane], __ATOMIC_RELAXED,
                                                __HIP_MEMORY_SCOPE_AGENT);
                unsigned f1 = __hip_atomic_load(&flags[64 + lane], __ATOMIC_RELAXED,
                                                __HIP_MEMORY_SCOPE_AGENT);
                if (__all(f0 >= tgt && f1 >= tgt)) break;
                __builtin_amdgcn_s_sleep(2);
            }
            // compiler-ordering fence only (workgroup scope: no cache ops)
            __builtin_amdgcn_fence(__ATOMIC_ACQUIRE, "workgroup");
        }
    }
}

// ---------------------------------------------------------------------------
// head: logits[b][n] = sum_k hT[k][b] * Wo[k][n] + bo[n]
// (final h lives in hbuf[0]: parity of t=512 is 0; inter-kernel release
// makes the scan's L3-resident h visible to normal loads here)
// ---------------------------------------------------------------------------
__global__ void head_kernel(const float* __restrict__ hT,
                            const float* __restrict__ Wo,
                            const float* __restrict__ bo,
                            float* __restrict__ out) {
    int tid = threadIdx.x;        // 128 threads
    int b = tid >> 1, n = tid & 1;
    float acc = bo[n];
#pragma unroll 8
    for (int k = 0; k < HIDDEN; ++k)
        acc = fmaf(hT[k * 64 + b], Wo[k * 2 + n], acc);
    out[b * 2 + n] = acc;
}

// ---------------------------------------------------------------------------
extern "C" void kernel_launch(void* const* d_in, const int* in_sizes, int n_in,
                              void* d_out, int out_size, void* d_ws, size_t ws_size,
                              hipStream_t stream) {
    (void)in_sizes; (void)n_in; (void)out_size; (void)ws_size;
    const int*   ids = (const int*)  d_in[0];
    const float* emb = (const float*)d_in[1];
    const float* Wx  = (const float*)d_in[2];
    const float* Wh  = (const float*)d_in[3];
    const float* bx  = (const float*)d_in[4];
    const float* bh  = (const float*)d_in[5];
    const float* Wo  = (const float*)d_in[6];
    const float* bo  = (const float*)d_in[7];
    float* out = (float*)d_out;

    char* ws = (char*)d_ws;
    // ws layout: [flags 1KB][hbuf 2*512*64 f32 = 256KB][whp 3MB][xg 192MB]
    unsigned* flags = (unsigned*)ws;
    float* hbuf = (float*)(ws + 1024);
    float* whp  = (float*)(ws + 1024 + 2 * HIDDEN * BATCH * 4);
    float* xg   = (float*)(ws + 1024 + 2 * HIDDEN * BATCH * 4 + NBLK * CPB * HIDDEN * 4);

    init_flags<<<dim3(1), dim3(NBLK), 0, stream>>>(flags);
    prep_wh<<<dim3(1536), dim3(512), 0, stream>>>(Wh, whp);
    xg_gemm<<<dim3(24, 512), dim3(256), 0, stream>>>(ids, emb, Wx, bx, xg);
    gru_scan<<<dim3(NBLK), dim3(512), 0, stream>>>(whp, xg, bh, hbuf, flags);
    head_kernel<<<dim3(1), dim3(128), 0, stream>>>(hbuf, Wo, bo, out);
}